// Round 11
// baseline (265.217 us; speedup 1.0000x reference)
//
#include <hip/hip_runtime.h>
#include <hip/hip_bf16.h>

// SGNHeadLSS — round 17: ALL WEIGHTS IN REGISTERS, persistent blocks.
// r16 post-mortem (decisive null): occupancy 37->74%, VALUBusy 20->33%,
// per-wave work halved => dur UNCHANGED (~80-82us). Concurrency in any
// form (blocks r9, ILP r12, waves r16) is not the lever. What remains
// on every phase's critical path in every structure: acquiring the same
// 61KB of weights per tile (VMEM or LDS stage; L1=32KB thrashes).
// Fix: r16 column-split needs only 30 b-frags/wave = 120 VGPR for ALL
// five weight matrices -> load ONCE in a persistent-block prologue
// (grid 256 = 1 block/CU, TILES=16), loop tiles; GEMM phases become
// pure {ds_read -> MFMA}, zero VMEM. Biases hoisted too (13 VGPR).
// Peak ~178 VGPR < 256 cap at launch_bounds(512,2); static indexing
// throughout. 6 barriers/tile (ordering audited for sX/sRank/sOut
// cross-tile reuse). Math identical to r16 (passed, absmax 0.0156).

#define NVOX 262144
#define NU   65536
#define NM   196608
#define CIN  128
#define CHALF 64
#define NCLS 20
#define TR   64
#define TILES 16
#define NBLK (NVOX / (TR * TILES))  // 256

#define SXS 136   // sX row stride in u16 (272B)
#define SHS 68    // sH row stride in u16 (136B)
#define SOS 21    // sOut row stride in f32

// ws layout (u16 units), fragment order: [nt][kc][lane]*8
#define W1F  0       // nt4 kc4  -> 8192
#define W2F  8192    // nt8 kc2  -> 8192
#define SDBF 16384   // nt4 kc4  -> 8192
#define SSCF 24576   // nt2 kc2  -> 2048
#define AUXF 26624   // nt2 kc4  -> 4096
#define WS_WT 30720  // 61440 bytes of weights; rank[NVOX] int32 follows

typedef unsigned short u16;
typedef short    bf16x4 __attribute__((ext_vector_type(4)));
typedef short    bf16x8 __attribute__((ext_vector_type(8)));
typedef float    f32x4  __attribute__((ext_vector_type(4)));

__device__ __forceinline__ u16 f2b(float f) {
    __hip_bfloat16 h = __float2bfloat16(f);
    return *(u16*)&h;
}

// B-frag layout: lane=q*16+n15 holds B[k=kc*32+q*8+j][n=nt*16+n15], j=0..7
__global__ void prep_weights(const float* __restrict__ w1,  const float* __restrict__ w2,
                             const float* __restrict__ sdbw,const float* __restrict__ sscw,
                             const float* __restrict__ auxw,
                             const int* __restrict__ uidx,  const int* __restrict__ midx,
                             u16* __restrict__ ws) {
    int i = blockIdx.x * blockDim.x + threadIdx.x;
    const int stride = gridDim.x * blockDim.x;
    int* __restrict__ rank = (int*)(ws + WS_WT);
    for (int t = i; t < NU; t += stride) rank[uidx[t]] = t;
    for (int t = i; t < NM; t += stride) rank[midx[t]] = -1;
    for (; i < WS_WT; i += stride) {
        float v;
        if (i < W2F) {                      // w1^frag: N=64, K=128
            int t = i, j = t & 7, lane = (t >> 3) & 63, kc = (t >> 9) & 3, nt = t >> 11;
            int k = kc*32 + (lane >> 4)*8 + j, n = nt*16 + (lane & 15);
            v = w1[k*CHALF + n];
        } else if (i < SDBF) {              // w2^frag: N=128, K=64
            int t = i - W2F, j = t & 7, lane = (t >> 3) & 63, kc = (t >> 9) & 1, nt = t >> 10;
            int k = kc*32 + (lane >> 4)*8 + j, n = nt*16 + (lane & 15);
            v = w2[k*CIN + n];
        } else if (i < SSCF) {              // sdb^frag: N=64, K=128
            int t = i - SDBF, j = t & 7, lane = (t >> 3) & 63, kc = (t >> 9) & 3, nt = t >> 11;
            int k = kc*32 + (lane >> 4)*8 + j, n = nt*16 + (lane & 15);
            v = sdbw[k*CHALF + n];
        } else if (i < AUXF) {              // ssc^frag: N=32(pad), K=64
            int t = i - SSCF, j = t & 7, lane = (t >> 3) & 63, kc = (t >> 9) & 1, nt = t >> 10;
            int k = kc*32 + (lane >> 4)*8 + j, n = nt*16 + (lane & 15);
            v = (n < NCLS) ? sscw[k*NCLS + n] : 0.f;
        } else {                            // aux^frag: N=32(pad), K=128
            int t = i - AUXF, j = t & 7, lane = (t >> 3) & 63, kc = (t >> 9) & 3, nt = t >> 11;
            int k = kc*32 + (lane >> 4)*8 + j, n = nt*16 + (lane & 15);
            v = (n < NCLS) ? auxw[k*NCLS + n] : 0.f;
        }
        ws[i] = f2b(v);
    }
}

__global__ __launch_bounds__(512, 2)
void sgn_mfma(const float* __restrict__ x3d,
              const float* __restrict__ b1,   const float* __restrict__ lng,
              const float* __restrict__ lnb,  const float* __restrict__ bb2,
              const float* __restrict__ sdbb, const float* __restrict__ sscb,
              const float* __restrict__ auxb,
              const int* __restrict__ rank,   const u16* __restrict__ wt,
              float* __restrict__ out)
{
    __shared__ __align__(16) u16 sX[TR * SXS];      // feats / vox   17408B
    __shared__ __align__(16) u16 sH[TR * SHS];      // h / d          8704B
    __shared__ __align__(16) float sOut[TR * SOS];  // ssc logits     5376B
    __shared__ float sLN[TR][2][2];                 // LN partials    1024B
    __shared__ int sRank[TR];                       //                 256B

    const int tid  = threadIdx.x;
    const int base = (int)blockIdx.x * (TR * TILES);

    const int w    = tid >> 6;             // wave 0..7
    const int half = w & 1;                // column half of the pair
    const int m0   = (w >> 1) * 16;        // shared 16-row slice
    const int lane = tid & 63;
    const int q    = lane >> 4;
    const int n15  = lane & 15;
    const int kq   = q * 8;

    // ---- prologue: hoist ALL weight fragments into registers (once) ----
    const int ntb  = half * 2;             // W1/SDB column base
    const int ntb2 = half * 4;             // W2 column base
    bf16x8 w1r[8], w2r[8], sdbr[8], sscr[2], auxr[4];
    #pragma unroll
    for (int i = 0; i < 2; ++i)
        #pragma unroll
        for (int kc = 0; kc < 4; ++kc) {
            w1r [i*4 + kc] = *(const bf16x8*)&wt[W1F  + (((ntb+i)*4 + kc)*64 + lane)*8];
            sdbr[i*4 + kc] = *(const bf16x8*)&wt[SDBF + (((ntb+i)*4 + kc)*64 + lane)*8];
        }
    #pragma unroll
    for (int i = 0; i < 4; ++i)
        #pragma unroll
        for (int kc = 0; kc < 2; ++kc)
            w2r[i*2 + kc] = *(const bf16x8*)&wt[W2F + (((ntb2+i)*2 + kc)*64 + lane)*8];
    #pragma unroll
    for (int kc = 0; kc < 2; ++kc)
        sscr[kc] = *(const bf16x8*)&wt[SSCF + ((half*2 + kc)*64 + lane)*8];
    #pragma unroll
    for (int kc = 0; kc < 4; ++kc)
        auxr[kc] = *(const bf16x8*)&wt[AUXF + ((half*4 + kc)*64 + lane)*8];

    // ---- hoist bias / LN scalars ----
    float b1v[2], gv[2], ev[2], sdbbv[2], b2v[4];
    #pragma unroll
    for (int i = 0; i < 2; ++i) {
        b1v[i]   = b1  [(ntb+i)*16 + n15];
        gv[i]    = lng [(ntb+i)*16 + n15];
        ev[i]    = lnb [(ntb+i)*16 + n15];
        sdbbv[i] = sdbb[(ntb+i)*16 + n15];
    }
    #pragma unroll
    for (int i = 0; i < 4; ++i) b2v[i] = bb2[(ntb2+i)*16 + n15];
    const int  colh  = half*16 + n15;
    const float sscbv = (colh < NCLS) ? sscb[colh] : 0.f;
    const float auxbv = (colh < NCLS) ? auxb[colh] : 0.f;

    // pack-phase thread mapping
    const int gch = (tid >> 4) * 4;   // channel quad
    const int vp  = (tid & 15) * 4;   // voxel quad

    #pragma unroll 1
    for (int t = 0; t < TILES; ++t) {
        const int p0 = base + t * TR;

        // ---- pack: 4 channels x 4 vox per thread ----
        {
            f32x4 cv[4];
            #pragma unroll
            for (int r = 0; r < 4; ++r)
                cv[r] = *(const f32x4*)&x3d[(size_t)(gch + r) * NVOX + p0 + vp];
            #pragma unroll
            for (int j = 0; j < 4; ++j) {
                bf16x4 row;
                #pragma unroll
                for (int r = 0; r < 4; ++r) ((u16*)&row)[r] = f2b(cv[r][j]);
                *(bf16x4*)&sX[(vp + j) * SXS + gch] = row;
            }
        }
        if (tid < TR) sRank[tid] = rank[p0 + tid];
        __syncthreads();                   // B1: sX + sRank

        // ---- GEMM1: feats @ w1 (nt = ntb+{0,1}) ----
        {
            f32x4 acc[2];
            #pragma unroll
            for (int i = 0; i < 2; ++i) acc[i] = (f32x4){b1v[i], b1v[i], b1v[i], b1v[i]};
            bf16x8 af[4];
            #pragma unroll
            for (int kc = 0; kc < 4; ++kc)
                af[kc] = *(const bf16x8*)&sX[(m0 + n15) * SXS + kc*32 + kq];
            #pragma unroll
            for (int kc = 0; kc < 4; ++kc)
                #pragma unroll
                for (int i = 0; i < 2; ++i)
                    acc[i] = __builtin_amdgcn_mfma_f32_16x16x32_bf16(af[kc], w1r[i*4+kc], acc[i], 0, 0, 0);
            // partial LN sums over this half's 32 cols
            float s1v[4], s2v[4];
            #pragma unroll
            for (int reg = 0; reg < 4; ++reg) {
                float s1 = acc[0][reg] + acc[1][reg];
                float s2 = acc[0][reg]*acc[0][reg] + acc[1][reg]*acc[1][reg];
                #pragma unroll
                for (int m = 1; m <= 8; m <<= 1) {
                    s1 += __shfl_xor(s1, m, 64);
                    s2 += __shfl_xor(s2, m, 64);
                }
                s1v[reg] = s1; s2v[reg] = s2;
            }
            if (n15 == 0) {
                #pragma unroll
                for (int reg = 0; reg < 4; ++reg) {
                    const int row = m0 + q*4 + reg;
                    sLN[row][half][0] = s1v[reg];
                    sLN[row][half][1] = s2v[reg];
                }
            }
            __syncthreads();               // B2: LN partials exchanged
            #pragma unroll
            for (int reg = 0; reg < 4; ++reg) {
                const int row = m0 + q*4 + reg;
                const float s1 = s1v[reg] + sLN[row][half^1][0];
                const float s2 = s2v[reg] + sLN[row][half^1][1];
                const float mu  = s1 * (1.f/64.f);
                const float var = s2 * (1.f/64.f) - mu*mu;
                const float rs  = rsqrtf(var + 1e-5f);
                #pragma unroll
                for (int i = 0; i < 2; ++i) {
                    float h = (acc[i][reg] - mu) * rs * gv[i] + ev[i];
                    h = h > 0.f ? h : 0.01f*h;
                    sH[row * SHS + (ntb+i)*16 + n15] = f2b(h);
                }
            }
        }
        __syncthreads();                   // B3: sH (h) complete

        // ---- GEMM2: h @ w2 -> prior (nt = ntb2+{0..3}) ----
        {
            f32x4 acc2[4];
            #pragma unroll
            for (int i = 0; i < 4; ++i) acc2[i] = (f32x4){b2v[i], b2v[i], b2v[i], b2v[i]};
            bf16x8 af2[2];
            #pragma unroll
            for (int kc = 0; kc < 2; ++kc)
                af2[kc] = *(const bf16x8*)&sH[(m0 + n15) * SHS + kc*32 + kq];
            #pragma unroll
            for (int kc = 0; kc < 2; ++kc)
                #pragma unroll
                for (int i = 0; i < 4; ++i)
                    acc2[i] = __builtin_amdgcn_mfma_f32_16x16x32_bf16(af2[kc], w2r[i*2+kc], acc2[i], 0, 0, 0);
            #pragma unroll
            for (int reg = 0; reg < 4; ++reg) {
                const int row = m0 + q*4 + reg;
                if (sRank[row] < 0) {      // masked -> vox = prior (this half's cols)
                    #pragma unroll
                    for (int i = 0; i < 4; ++i)
                        sX[row * SXS + (ntb2+i)*16 + n15] = f2b(acc2[i][reg]);
                }
            }
        }
        __syncthreads();                   // B4: sX select complete

        // ---- SDB: vox @ sdb_w -> leaky -> d (nt = ntb+{0,1}) ----
        {
            f32x4 accd[2];
            #pragma unroll
            for (int i = 0; i < 2; ++i) accd[i] = (f32x4){sdbbv[i], sdbbv[i], sdbbv[i], sdbbv[i]};
            bf16x8 af[4];
            #pragma unroll
            for (int kc = 0; kc < 4; ++kc)
                af[kc] = *(const bf16x8*)&sX[(m0 + n15) * SXS + kc*32 + kq];
            #pragma unroll
            for (int kc = 0; kc < 4; ++kc)
                #pragma unroll
                for (int i = 0; i < 2; ++i)
                    accd[i] = __builtin_amdgcn_mfma_f32_16x16x32_bf16(af[kc], sdbr[i*4+kc], accd[i], 0, 0, 0);
            #pragma unroll
            for (int reg = 0; reg < 4; ++reg) {
                const int row = m0 + q*4 + reg;
                #pragma unroll
                for (int i = 0; i < 2; ++i) {
                    float vv = accd[i][reg];
                    vv = vv > 0.f ? vv : 0.01f*vv;
                    sH[row * SHS + (ntb+i)*16 + n15] = f2b(vv);
                }
            }
        }
        __syncthreads();                   // B5: sH (d) complete

        // ---- SSC: d @ ssc_w (nt = half) -> sOut ----
        {
            f32x4 accs = (f32x4){sscbv, sscbv, sscbv, sscbv};
            bf16x8 af2[2];
            #pragma unroll
            for (int kc = 0; kc < 2; ++kc)
                af2[kc] = *(const bf16x8*)&sH[(m0 + n15) * SHS + kc*32 + kq];
            #pragma unroll
            for (int kc = 0; kc < 2; ++kc)
                accs = __builtin_amdgcn_mfma_f32_16x16x32_bf16(af2[kc], sscr[kc], accs, 0, 0, 0);
            #pragma unroll
            for (int reg = 0; reg < 4; ++reg) {
                const int row = m0 + q*4 + reg;
                if (half == 0)      sOut[row*SOS + n15] = accs[reg];
                else if (n15 < 4)   sOut[row*SOS + 16 + n15] = accs[reg];
            }
        }

        // ---- AUX: feats @ aux_w (nt = half); store unmasked ----
        {
            f32x4 acca = (f32x4){auxbv, auxbv, auxbv, auxbv};
            bf16x8 af[4];
            #pragma unroll
            for (int kc = 0; kc < 4; ++kc)
                af[kc] = *(const bf16x8*)&sX[(m0 + n15) * SXS + kc*32 + kq];
            #pragma unroll
            for (int kc = 0; kc < 4; ++kc)
                acca = __builtin_amdgcn_mfma_f32_16x16x32_bf16(af[kc], auxr[kc], acca, 0, 0, 0);
            const size_t abase = (size_t)NCLS * NVOX;
            #pragma unroll
            for (int reg = 0; reg < 4; ++reg) {
                const int rk = sRank[m0 + q*4 + reg];
                if (rk >= 0) {
                    if (half == 0)      out[abase + (size_t)rk * NCLS + n15] = acca[reg];
                    else if (n15 < 4)   out[abase + (size_t)rk * NCLS + 16 + n15] = acca[reg];
                }
            }
        }
        __syncthreads();                   // B6: sOut complete; sX/sRank reads done

        // ---- coalesced SSC store: out[ch][p0+vox] <- sOut[vox][ch] ----
        #pragma unroll
        for (int jj = 0; jj < 2; ++jj) {
            const int i = tid + jj*512;    // i = ch*64 + vox
            out[(size_t)(i >> 6) * NVOX + p0 + (i & 63)] = sOut[(i & 63) * SOS + (i >> 6)];
        }
        {
            const int i = tid + 1024;
            if (i < 1280)
                out[(size_t)(i >> 6) * NVOX + p0 + (i & 63)] = sOut[(i & 63) * SOS + (i >> 6)];
        }
        // next tile's pack (writes sX/sRank) is ordered behind B6 for
        // all waves; sOut next written only after B5(t+1).
    }
}

extern "C" void kernel_launch(void* const* d_in, const int* in_sizes, int n_in,
                              void* d_out, int out_size, void* d_ws, size_t ws_size,
                              hipStream_t stream) {
    const float* x3d  = (const float*)d_in[0];
    const float* w1   = (const float*)d_in[1];
    const float* b1   = (const float*)d_in[2];
    const float* lng  = (const float*)d_in[3];
    const float* lnb  = (const float*)d_in[4];
    const float* w2   = (const float*)d_in[5];
    const float* bb2  = (const float*)d_in[6];
    const float* sdbw = (const float*)d_in[7];
    const float* sdbb = (const float*)d_in[8];
    const float* sscw = (const float*)d_in[9];
    const float* sscb = (const float*)d_in[10];
    const float* auxw = (const float*)d_in[11];
    const float* auxb = (const float*)d_in[12];
    const int*   uidx = (const int*)d_in[13];
    const int*   midx = (const int*)d_in[14];
    float* out = (float*)d_out;
    u16*   wt  = (u16*)d_ws;
    const int* rank = (const int*)((const char*)d_ws + WS_WT*2);

    hipLaunchKernelGGL(prep_weights, dim3(128), dim3(256), 0, stream,
                       w1, w2, sdbw, sscw, auxw, uidx, midx, wt);
    hipLaunchKernelGGL(sgn_mfma, dim3(NBLK), dim3(512), 0, stream,
                       x3d, b1, lng, lnb, bb2, sdbb, sscb, auxb,
                       rank, wt, out);
}

// Round 12
// 253.942 us; speedup vs baseline: 1.0444x; 1.0444x over previous
//
#include <hip/hip_runtime.h>
#include <hip/hip_bf16.h>

// SGNHeadLSS — round 18: FOLD GEMM2∘SDB algebraically; 3-stage chain.
// r17 post-mortem: weights-in-regs + 1 blk/CU = 98us (barrier convoy,
// no co-resident overlap). Ledger: 10 structures, all pipes <35%, all
// 80-100us; concurrency/weight-path/traffic eliminated. Shared culprit:
// 5-deep dependent GEMM chain per tile. Fix is algebra: masked
// d = leaky(prior@sdbw+sdbb) = leaky(h@(w2@sdbw) + (b2@sdbw+sdbb));
// precompute W2S[64x64], b2s[64] in prep. Unmasked d = leaky(feats@
// sdbw+sdbb); leaky commutes with row-select => select at d level in
// REGISTERS. Chain: {G1 || SDBf || AUX: 40 indep MFMAs off one a-frag
// set} -> {Gh(W2S): 8} -> {SSC: 4}. No prior materialization, no sX
// overwrite. r14 shell: 256 thr, wave-private rows, full-wave LN,
// 2 barriers, direct global b-frags, r14 pack. (256,3): peak ~110 VGPR
// < 168 cap. Fewer roundings than r14 path (W2S folded in f32).

#define NVOX 262144
#define NU   65536
#define NM   196608
#define CIN  128
#define CHALF 64
#define NCLS 20
#define TR   64
#define NBLK (NVOX / TR)  // 4096

#define SXS 136   // sX row stride in u16 (272B)
#define SHS 72    // sH row stride in u16 (144B)
#define SOS 21    // sOut row stride in f32

// ws layout (u16 units), fragment order: [nt][kc][lane]*8
#define W1F  0       // w1^frag   nt4 kc4 -> 8192
#define SDBF 8192    // sdb^frag  nt4 kc4 -> 8192
#define W2SF 16384   // W2S^frag  nt4 kc2 -> 4096  (W2S = w2 @ sdbw, 64x64)
#define SSCF 20480   // ssc^frag  nt2 kc2 -> 2048
#define AUXF 22528   // aux^frag  nt2 kc4 -> 4096
#define WS_END 26624 // u16 count; b2s f32[64] follows, then rank
#define B2S_BYTE (WS_END * 2)          // 53248
#define RANK_BYTE (B2S_BYTE + 256)     // 53504

typedef unsigned short u16;
typedef short    bf16x8 __attribute__((ext_vector_type(8)));
typedef float    f32x4  __attribute__((ext_vector_type(4)));

__device__ __forceinline__ u16 f2b(float f) {
    __hip_bfloat16 h = __float2bfloat16(f);
    return *(u16*)&h;
}

// B-frag layout: lane=q*16+n15 holds B[k=kc*32+q*8+j][n=nt*16+n15], j=0..7
__global__ void prep_weights(const float* __restrict__ w1,  const float* __restrict__ w2,
                             const float* __restrict__ b2,  const float* __restrict__ sdbw,
                             const float* __restrict__ sdbb,const float* __restrict__ sscw,
                             const float* __restrict__ auxw,
                             const int* __restrict__ uidx,  const int* __restrict__ midx,
                             u16* __restrict__ ws) {
    int i = blockIdx.x * blockDim.x + threadIdx.x;
    const int stride = gridDim.x * blockDim.x;
    int*   __restrict__ rank = (int*)((char*)ws + RANK_BYTE);
    float* __restrict__ b2s  = (float*)((char*)ws + B2S_BYTE);
    for (int t = i; t < NU; t += stride) rank[uidx[t]] = t;
    for (int t = i; t < NM; t += stride) rank[midx[t]] = -1;
    // b2s[j] = sum_c b2[c]*sdbw[c][j] + sdbb[j]
    for (int j = i; j < CHALF; j += stride) {
        float s = sdbb[j];
        for (int c = 0; c < CIN; ++c) s += b2[c] * sdbw[c*CHALF + j];
        b2s[j] = s;
    }
    for (; i < WS_END; i += stride) {
        float v;
        if (i < SDBF) {                     // w1^frag: N=64, K=128
            int t = i, j = t & 7, lane = (t >> 3) & 63, kc = (t >> 9) & 3, nt = t >> 11;
            int k = kc*32 + (lane >> 4)*8 + j, n = nt*16 + (lane & 15);
            v = w1[k*CHALF + n];
        } else if (i < W2SF) {              // sdb^frag: N=64, K=128
            int t = i - SDBF, j = t & 7, lane = (t >> 3) & 63, kc = (t >> 9) & 3, nt = t >> 11;
            int k = kc*32 + (lane >> 4)*8 + j, n = nt*16 + (lane & 15);
            v = sdbw[k*CHALF + n];
        } else if (i < SSCF) {              // W2S^frag: N=64, K=64 (on-the-fly fold)
            int t = i - W2SF, j = t & 7, lane = (t >> 3) & 63, kc = (t >> 9) & 1, nt = t >> 10;
            int k = kc*32 + (lane >> 4)*8 + j, n = nt*16 + (lane & 15);
            float s = 0.f;
            for (int c = 0; c < CIN; ++c) s += w2[k*CIN + c] * sdbw[c*CHALF + n];
            v = s;
        } else if (i < AUXF) {              // ssc^frag: N=32(pad), K=64
            int t = i - SSCF, j = t & 7, lane = (t >> 3) & 63, kc = (t >> 9) & 1, nt = t >> 10;
            int k = kc*32 + (lane >> 4)*8 + j, n = nt*16 + (lane & 15);
            v = (n < NCLS) ? sscw[k*NCLS + n] : 0.f;
        } else {                            // aux^frag: N=32(pad), K=128
            int t = i - AUXF, j = t & 7, lane = (t >> 3) & 63, kc = (t >> 9) & 3, nt = t >> 11;
            int k = kc*32 + (lane >> 4)*8 + j, n = nt*16 + (lane & 15);
            v = (n < NCLS) ? auxw[k*NCLS + n] : 0.f;
        }
        ws[i] = f2b(v);
    }
}

__global__ __launch_bounds__(256, 3)
void sgn_mfma(const float* __restrict__ x3d,
              const float* __restrict__ b1,   const float* __restrict__ lng,
              const float* __restrict__ lnb,  const float* __restrict__ b2s,
              const float* __restrict__ sdbb, const float* __restrict__ sscb,
              const float* __restrict__ auxb,
              const int* __restrict__ rank,   const u16* __restrict__ wt,
              float* __restrict__ out)
{
    __shared__ __align__(16) u16 sX[TR * SXS];      // feats       17408B
    __shared__ __align__(16) u16 sH[TR * SHS];      // h / d        9216B
    __shared__ __align__(16) float sOut[TR * SOS];  // ssc logits   5376B
    __shared__ int sRank[TR];

    const int tid = threadIdx.x;
    const int p0  = (int)blockIdx.x * TR;

    // ---- pack (r14): 8 channels x 4 vox/thread; 4x ds_write_b128 ----
    {
        const int gch = (tid >> 4) * 8;
        const int vp  = (tid & 15) * 4;
        f32x4 cv[8];
        #pragma unroll
        for (int r = 0; r < 8; ++r)
            cv[r] = *(const f32x4*)&x3d[(size_t)(gch + r) * NVOX + p0 + vp];
        #pragma unroll
        for (int j = 0; j < 4; ++j) {
            bf16x8 row;
            #pragma unroll
            for (int r = 0; r < 8; ++r) ((u16*)&row)[r] = f2b(cv[r][j]);
            *(bf16x8*)&sX[(vp + j) * SXS + gch] = row;
        }
    }
    if (tid < TR) sRank[tid] = rank[p0 + tid];
    __syncthreads();   // barrier 1: sX + sRank cross-wave

    const int m0   = (tid >> 6) * 16;  // wave's 16 rows (private hereafter)
    const int lane = tid & 63;
    const int q    = lane >> 4;
    const int n15  = lane & 15;
    const int kq   = q * 8;

    // ---- stage A: G1(w1) + SDBf(sdbw) + AUX(auxw), all from sX ----
    f32x4 accf[4];                          // dF: survives into stage B
    {
        f32x4 accg[4], acca[2];
        #pragma unroll
        for (int nt = 0; nt < 4; ++nt) {
            const float bg = b1[nt*16 + n15];
            const float bf_ = sdbb[nt*16 + n15];
            accg[nt] = (f32x4){bg, bg, bg, bg};
            accf[nt] = (f32x4){bf_, bf_, bf_, bf_};
        }
        #pragma unroll
        for (int nt = 0; nt < 2; ++nt) {
            const int col = nt*16 + n15;
            const float b = (col < NCLS) ? auxb[col] : 0.f;
            acca[nt] = (f32x4){b, b, b, b};
        }
        bf16x8 af[4];
        #pragma unroll
        for (int kc = 0; kc < 4; ++kc)
            af[kc] = *(const bf16x8*)&sX[(m0 + n15) * SXS + kc*32 + kq];
        #pragma unroll
        for (int kc = 0; kc < 4; ++kc) {
            bf16x8 bw[4];
            #pragma unroll
            for (int nt = 0; nt < 4; ++nt)
                bw[nt] = *(const bf16x8*)&wt[W1F + ((nt*4 + kc)*64 + lane)*8];
            #pragma unroll
            for (int nt = 0; nt < 4; ++nt)
                accg[nt] = __builtin_amdgcn_mfma_f32_16x16x32_bf16(af[kc], bw[nt], accg[nt], 0, 0, 0);
        }
        #pragma unroll
        for (int kc = 0; kc < 4; ++kc) {
            bf16x8 bw[4];
            #pragma unroll
            for (int nt = 0; nt < 4; ++nt)
                bw[nt] = *(const bf16x8*)&wt[SDBF + ((nt*4 + kc)*64 + lane)*8];
            #pragma unroll
            for (int nt = 0; nt < 4; ++nt)
                accf[nt] = __builtin_amdgcn_mfma_f32_16x16x32_bf16(af[kc], bw[nt], accf[nt], 0, 0, 0);
        }
        #pragma unroll
        for (int kc = 0; kc < 4; ++kc) {
            bf16x8 bw[2];
            #pragma unroll
            for (int nt = 0; nt < 2; ++nt)
                bw[nt] = *(const bf16x8*)&wt[AUXF + ((nt*4 + kc)*64 + lane)*8];
            #pragma unroll
            for (int nt = 0; nt < 2; ++nt)
                acca[nt] = __builtin_amdgcn_mfma_f32_16x16x32_bf16(af[kc], bw[nt], acca[nt], 0, 0, 0);
        }
        // AUX store now (frees acca; predicated on unmasked)
        {
            const size_t abase = (size_t)NCLS * NVOX;
            #pragma unroll
            for (int reg = 0; reg < 4; ++reg) {
                const int rk = sRank[m0 + q*4 + reg];
                if (rk >= 0) {
                    out[abase + (size_t)rk * NCLS + n15] = acca[0][reg];
                    if (n15 < 4)
                        out[abase + (size_t)rk * NCLS + 16 + n15] = acca[1][reg];
                }
            }
        }
        // LN -> leaky -> h -> sH (full-wave shuffles, r14)
        float gv[4], ev[4];
        #pragma unroll
        for (int nt = 0; nt < 4; ++nt) { gv[nt] = lng[nt*16 + n15]; ev[nt] = lnb[nt*16 + n15]; }
        #pragma unroll
        for (int reg = 0; reg < 4; ++reg) {
            float s1 = accg[0][reg] + accg[1][reg] + accg[2][reg] + accg[3][reg];
            float s2 = accg[0][reg]*accg[0][reg] + accg[1][reg]*accg[1][reg]
                     + accg[2][reg]*accg[2][reg] + accg[3][reg]*accg[3][reg];
            #pragma unroll
            for (int m = 1; m <= 8; m <<= 1) {
                s1 += __shfl_xor(s1, m, 64);
                s2 += __shfl_xor(s2, m, 64);
            }
            const float mu  = s1 * (1.f/64.f);
            const float var = s2 * (1.f/64.f) - mu*mu;
            const float rs  = rsqrtf(var + 1e-5f);
            #pragma unroll
            for (int nt = 0; nt < 4; ++nt) {
                float h = (accg[nt][reg] - mu) * rs * gv[nt] + ev[nt];
                h = h > 0.f ? h : 0.01f*h;
                sH[(m0 + q*4 + reg) * SHS + nt*16 + n15] = f2b(h);
            }
        }
        // leaky on accf -> dF (in place)
        #pragma unroll
        for (int nt = 0; nt < 4; ++nt)
            #pragma unroll
            for (int reg = 0; reg < 4; ++reg) {
                const float v = accf[nt][reg];
                accf[nt][reg] = v > 0.f ? v : 0.01f*v;
            }
    }
    // no barrier: sH rows are wave-private (same wave writes then reads)

    // ---- stage B: h @ W2S -> leaky -> dM; select d; write d -> sH ----
    {
        f32x4 acch[4];
        #pragma unroll
        for (int nt = 0; nt < 4; ++nt) {
            const float b = b2s[nt*16 + n15];
            acch[nt] = (f32x4){b, b, b, b};
        }
        bf16x8 ah[2];
        #pragma unroll
        for (int kc = 0; kc < 2; ++kc)
            ah[kc] = *(const bf16x8*)&sH[(m0 + n15) * SHS + kc*32 + kq];
        #pragma unroll
        for (int kc = 0; kc < 2; ++kc) {
            bf16x8 bw[4];
            #pragma unroll
            for (int nt = 0; nt < 4; ++nt)
                bw[nt] = *(const bf16x8*)&wt[W2SF + ((nt*2 + kc)*64 + lane)*8];
            #pragma unroll
            for (int nt = 0; nt < 4; ++nt)
                acch[nt] = __builtin_amdgcn_mfma_f32_16x16x32_bf16(ah[kc], bw[nt], acch[nt], 0, 0, 0);
        }
        #pragma unroll
        for (int reg = 0; reg < 4; ++reg) {
            const int row = m0 + q*4 + reg;
            const bool masked = (sRank[row] < 0);
            #pragma unroll
            for (int nt = 0; nt < 4; ++nt) {
                float dm = acch[nt][reg];
                dm = dm > 0.f ? dm : 0.01f*dm;
                const float d = masked ? dm : accf[nt][reg];
                sH[row * SHS + nt*16 + n15] = f2b(d);
            }
        }
    }
    // no barrier: wave-private rows again

    // ---- stage C: d @ ssc_w -> sOut ----
    {
        f32x4 accs[2];
        #pragma unroll
        for (int nt = 0; nt < 2; ++nt) {
            const int col = nt*16 + n15;
            const float b = (col < NCLS) ? sscb[col] : 0.f;
            accs[nt] = (f32x4){b, b, b, b};
        }
        bf16x8 ad[2];
        #pragma unroll
        for (int kc = 0; kc < 2; ++kc)
            ad[kc] = *(const bf16x8*)&sH[(m0 + n15) * SHS + kc*32 + kq];
        #pragma unroll
        for (int kc = 0; kc < 2; ++kc) {
            bf16x8 bw[2];
            #pragma unroll
            for (int nt = 0; nt < 2; ++nt)
                bw[nt] = *(const bf16x8*)&wt[SSCF + ((nt*2 + kc)*64 + lane)*8];
            #pragma unroll
            for (int nt = 0; nt < 2; ++nt)
                accs[nt] = __builtin_amdgcn_mfma_f32_16x16x32_bf16(ad[kc], bw[nt], accs[nt], 0, 0, 0);
        }
        #pragma unroll
        for (int reg = 0; reg < 4; ++reg) {
            const int row = m0 + q*4 + reg;
            sOut[row*SOS + n15] = accs[0][reg];
            if (n15 < 4) sOut[row*SOS + 16 + n15] = accs[1][reg];
        }
    }
    __syncthreads();   // barrier 2: sOut complete (cross-wave readback)

    // ---- coalesced SSC store: out[ch][p0+vox] <- sOut[vox][ch] ----
    #pragma unroll
    for (int jj = 0; jj < 5; ++jj) {
        const int i = tid + jj*256;       // i = ch*64 + vox
        out[(size_t)(i >> 6) * NVOX + p0 + (i & 63)] = sOut[(i & 63) * SOS + (i >> 6)];
    }
}

extern "C" void kernel_launch(void* const* d_in, const int* in_sizes, int n_in,
                              void* d_out, int out_size, void* d_ws, size_t ws_size,
                              hipStream_t stream) {
    const float* x3d  = (const float*)d_in[0];
    const float* w1   = (const float*)d_in[1];
    const float* b1   = (const float*)d_in[2];
    const float* lng  = (const float*)d_in[3];
    const float* lnb  = (const float*)d_in[4];
    const float* w2   = (const float*)d_in[5];
    const float* bb2  = (const float*)d_in[6];
    const float* sdbw = (const float*)d_in[7];
    const float* sdbb = (const float*)d_in[8];
    const float* sscw = (const float*)d_in[9];
    const float* sscb = (const float*)d_in[10];
    const float* auxw = (const float*)d_in[11];
    const float* auxb = (const float*)d_in[12];
    const int*   uidx = (const int*)d_in[13];
    const int*   midx = (const int*)d_in[14];
    float* out = (float*)d_out;
    u16*   wt  = (u16*)d_ws;
    const float* b2s  = (const float*)((const char*)d_ws + B2S_BYTE);
    const int*   rank = (const int*)((const char*)d_ws + RANK_BYTE);

    hipLaunchKernelGGL(prep_weights, dim3(128), dim3(256), 0, stream,
                       w1, w2, bb2, sdbw, sdbb, sscw, auxw, uidx, midx, wt);
    hipLaunchKernelGGL(sgn_mfma, dim3(NBLK), dim3(256), 0, stream,
                       x3d, b1, lng, lnb, b2s, sdbb, sscb, auxb,
                       rank, wt, out);
}

// Round 13
// 252.061 us; speedup vs baseline: 1.0522x; 1.0075x over previous
//
#include <hip/hip_runtime.h>
#include <hip/hip_bf16.h>

// SGNHeadLSS — round 19: async LDS weight stage on the r18 fold.
// r18 post-mortem: fold cut 2 GEMM stages -> only -1.4us (78.5) =>
// chain DEPTH isn't the cost; per-stage serialized b-frag L2 latency is
// (VGPR=48 again: ~6 loads in flight; stage A = 40 L1-missing loads ->
// ~7 serialized groups x ~250cy). Register-based fixes all failed
// (r10/11/13 spill, r14 re-serialized, r17 occupancy). Untried path:
// __builtin_amdgcn_global_load_lds for WEIGHTS — zero VGPR, async,
// issued once at block top under the x3d load, drained by barrier 1's
// implicit vmcnt(0). Stage A b-frags become conflict-free ds_read_b128.
// W1+SDB (32KB) staged; AUX/W2S/SSC (off critical path / tiny) stay
// global. LDS 65024B -> 2 blocks/CU (2-4 blocks proven equivalent).
// Everything else verbatim r18 (passed, absmax 0.023).

#define NVOX 262144
#define NU   65536
#define NM   196608
#define CIN  128
#define CHALF 64
#define NCLS 20
#define TR   64
#define NBLK (NVOX / TR)  // 4096

#define SXS 136   // sX row stride in u16 (272B)
#define SHS 72    // sH row stride in u16 (144B)
#define SOS 21    // sOut row stride in f32

// ws layout (u16 units), fragment order: [nt][kc][lane]*8
#define W1F  0       // w1^frag   nt4 kc4 -> 8192
#define SDBF 8192    // sdb^frag  nt4 kc4 -> 8192
#define W2SF 16384   // W2S^frag  nt4 kc2 -> 4096  (W2S = w2 @ sdbw, 64x64)
#define SSCF 20480   // ssc^frag  nt2 kc2 -> 2048
#define AUXF 22528   // aux^frag  nt2 kc4 -> 4096
#define WS_END 26624 // u16 count; b2s f32[64] follows, then rank
#define B2S_BYTE (WS_END * 2)          // 53248
#define RANK_BYTE (B2S_BYTE + 256)     // 53504

typedef unsigned short u16;
typedef short    bf16x8 __attribute__((ext_vector_type(8)));
typedef float    f32x4  __attribute__((ext_vector_type(4)));

__device__ __forceinline__ u16 f2b(float f) {
    __hip_bfloat16 h = __float2bfloat16(f);
    return *(u16*)&h;
}

// B-frag layout: lane=q*16+n15 holds B[k=kc*32+q*8+j][n=nt*16+n15], j=0..7
__global__ void prep_weights(const float* __restrict__ w1,  const float* __restrict__ w2,
                             const float* __restrict__ b2,  const float* __restrict__ sdbw,
                             const float* __restrict__ sdbb,const float* __restrict__ sscw,
                             const float* __restrict__ auxw,
                             const int* __restrict__ uidx,  const int* __restrict__ midx,
                             u16* __restrict__ ws) {
    int i = blockIdx.x * blockDim.x + threadIdx.x;
    const int stride = gridDim.x * blockDim.x;
    int*   __restrict__ rank = (int*)((char*)ws + RANK_BYTE);
    float* __restrict__ b2s  = (float*)((char*)ws + B2S_BYTE);
    for (int t = i; t < NU; t += stride) rank[uidx[t]] = t;
    for (int t = i; t < NM; t += stride) rank[midx[t]] = -1;
    // b2s[j] = sum_c b2[c]*sdbw[c][j] + sdbb[j]
    for (int j = i; j < CHALF; j += stride) {
        float s = sdbb[j];
        for (int c = 0; c < CIN; ++c) s += b2[c] * sdbw[c*CHALF + j];
        b2s[j] = s;
    }
    for (; i < WS_END; i += stride) {
        float v;
        if (i < SDBF) {                     // w1^frag: N=64, K=128
            int t = i, j = t & 7, lane = (t >> 3) & 63, kc = (t >> 9) & 3, nt = t >> 11;
            int k = kc*32 + (lane >> 4)*8 + j, n = nt*16 + (lane & 15);
            v = w1[k*CHALF + n];
        } else if (i < W2SF) {              // sdb^frag: N=64, K=128
            int t = i - SDBF, j = t & 7, lane = (t >> 3) & 63, kc = (t >> 9) & 3, nt = t >> 11;
            int k = kc*32 + (lane >> 4)*8 + j, n = nt*16 + (lane & 15);
            v = sdbw[k*CHALF + n];
        } else if (i < SSCF) {              // W2S^frag: N=64, K=64 (on-the-fly fold)
            int t = i - W2SF, j = t & 7, lane = (t >> 3) & 63, kc = (t >> 9) & 1, nt = t >> 10;
            int k = kc*32 + (lane >> 4)*8 + j, n = nt*16 + (lane & 15);
            float s = 0.f;
            for (int c = 0; c < CIN; ++c) s += w2[k*CIN + c] * sdbw[c*CHALF + n];
            v = s;
        } else if (i < AUXF) {              // ssc^frag: N=32(pad), K=64
            int t = i - SSCF, j = t & 7, lane = (t >> 3) & 63, kc = (t >> 9) & 1, nt = t >> 10;
            int k = kc*32 + (lane >> 4)*8 + j, n = nt*16 + (lane & 15);
            v = (n < NCLS) ? sscw[k*NCLS + n] : 0.f;
        } else {                            // aux^frag: N=32(pad), K=128
            int t = i - AUXF, j = t & 7, lane = (t >> 3) & 63, kc = (t >> 9) & 3, nt = t >> 11;
            int k = kc*32 + (lane >> 4)*8 + j, n = nt*16 + (lane & 15);
            v = (n < NCLS) ? auxw[k*NCLS + n] : 0.f;
        }
        ws[i] = f2b(v);
    }
}

__global__ __launch_bounds__(256, 2)
void sgn_mfma(const float* __restrict__ x3d,
              const float* __restrict__ b1,   const float* __restrict__ lng,
              const float* __restrict__ lnb,  const float* __restrict__ b2s,
              const float* __restrict__ sdbb, const float* __restrict__ sscb,
              const float* __restrict__ auxb,
              const int* __restrict__ rank,   const u16* __restrict__ wt,
              float* __restrict__ out)
{
    __shared__ __align__(16) u16 wbuf[16384];       // W1+SDB frags  32768B
    __shared__ __align__(16) u16 sX[TR * SXS];      // feats         17408B
    __shared__ __align__(16) u16 sH[TR * SHS];      // h / d          9216B
    __shared__ __align__(16) float sOut[TR * SOS];  // ssc logits     5376B
    __shared__ int sRank[TR];                       //                 256B
    // total 65024B <= 64KB; 2 blocks/CU by LDS

    const int tid = threadIdx.x;
    const int p0  = (int)blockIdx.x * TR;

    // ---- async weight stage: W1+SDB frags -> wbuf (zero VGPR) ----
    // 32 chunks of 1KB (64 lanes x 16B); wave w issues chunks w*8..w*8+7.
    // Drained by barrier 1's implicit vmcnt(0).
    {
        const int w = tid >> 6, l = tid & 63;
        #pragma unroll
        for (int c8 = 0; c8 < 8; ++c8) {
            const int c = w*8 + c8;        // 0..31
            const u16* src = wt + ((c < 16) ? (W1F + c*512) : (SDBF + (c-16)*512)) + l*8;
            __builtin_amdgcn_global_load_lds(src, &wbuf[c*512], 16, 0, 0);
        }
    }

    // ---- pack (r14): 8 channels x 4 vox/thread; 4x ds_write_b128 ----
    {
        const int gch = (tid >> 4) * 8;
        const int vp  = (tid & 15) * 4;
        f32x4 cv[8];
        #pragma unroll
        for (int r = 0; r < 8; ++r)
            cv[r] = *(const f32x4*)&x3d[(size_t)(gch + r) * NVOX + p0 + vp];
        #pragma unroll
        for (int j = 0; j < 4; ++j) {
            bf16x8 row;
            #pragma unroll
            for (int r = 0; r < 8; ++r) ((u16*)&row)[r] = f2b(cv[r][j]);
            *(bf16x8*)&sX[(vp + j) * SXS + gch] = row;
        }
    }
    if (tid < TR) sRank[tid] = rank[p0 + tid];
    __syncthreads();   // barrier 1: sX + sRank + wbuf (async stage drained)

    const int m0   = (tid >> 6) * 16;  // wave's 16 rows (private hereafter)
    const int lane = tid & 63;
    const int q    = lane >> 4;
    const int n15  = lane & 15;
    const int kq   = q * 8;

    // ---- stage A: G1(w1) + SDBf(sdbw) from LDS wbuf + AUX(auxw) global ----
    f32x4 accf[4];                          // dF: survives into stage B
    {
        f32x4 accg[4], acca[2];
        #pragma unroll
        for (int nt = 0; nt < 4; ++nt) {
            const float bg = b1[nt*16 + n15];
            const float bf_ = sdbb[nt*16 + n15];
            accg[nt] = (f32x4){bg, bg, bg, bg};
            accf[nt] = (f32x4){bf_, bf_, bf_, bf_};
        }
        #pragma unroll
        for (int nt = 0; nt < 2; ++nt) {
            const int col = nt*16 + n15;
            const float b = (col < NCLS) ? auxb[col] : 0.f;
            acca[nt] = (f32x4){b, b, b, b};
        }
        bf16x8 af[4];
        #pragma unroll
        for (int kc = 0; kc < 4; ++kc)
            af[kc] = *(const bf16x8*)&sX[(m0 + n15) * SXS + kc*32 + kq];
        #pragma unroll
        for (int kc = 0; kc < 4; ++kc) {
            bf16x8 bw[4];
            #pragma unroll
            for (int nt = 0; nt < 4; ++nt)
                bw[nt] = *(const bf16x8*)&wbuf[((nt*4 + kc)*64 + lane)*8];
            #pragma unroll
            for (int nt = 0; nt < 4; ++nt)
                accg[nt] = __builtin_amdgcn_mfma_f32_16x16x32_bf16(af[kc], bw[nt], accg[nt], 0, 0, 0);
        }
        #pragma unroll
        for (int kc = 0; kc < 4; ++kc) {
            bf16x8 bw[4];
            #pragma unroll
            for (int nt = 0; nt < 4; ++nt)
                bw[nt] = *(const bf16x8*)&wbuf[8192 + ((nt*4 + kc)*64 + lane)*8];
            #pragma unroll
            for (int nt = 0; nt < 4; ++nt)
                accf[nt] = __builtin_amdgcn_mfma_f32_16x16x32_bf16(af[kc], bw[nt], accf[nt], 0, 0, 0);
        }
        #pragma unroll
        for (int kc = 0; kc < 4; ++kc) {
            bf16x8 bw[2];
            #pragma unroll
            for (int nt = 0; nt < 2; ++nt)
                bw[nt] = *(const bf16x8*)&wt[AUXF + ((nt*4 + kc)*64 + lane)*8];
            #pragma unroll
            for (int nt = 0; nt < 2; ++nt)
                acca[nt] = __builtin_amdgcn_mfma_f32_16x16x32_bf16(af[kc], bw[nt], acca[nt], 0, 0, 0);
        }
        // AUX store now (frees acca; predicated on unmasked)
        {
            const size_t abase = (size_t)NCLS * NVOX;
            #pragma unroll
            for (int reg = 0; reg < 4; ++reg) {
                const int rk = sRank[m0 + q*4 + reg];
                if (rk >= 0) {
                    out[abase + (size_t)rk * NCLS + n15] = acca[0][reg];
                    if (n15 < 4)
                        out[abase + (size_t)rk * NCLS + 16 + n15] = acca[1][reg];
                }
            }
        }
        // LN -> leaky -> h -> sH (full-wave shuffles)
        float gv[4], ev[4];
        #pragma unroll
        for (int nt = 0; nt < 4; ++nt) { gv[nt] = lng[nt*16 + n15]; ev[nt] = lnb[nt*16 + n15]; }
        #pragma unroll
        for (int reg = 0; reg < 4; ++reg) {
            float s1 = accg[0][reg] + accg[1][reg] + accg[2][reg] + accg[3][reg];
            float s2 = accg[0][reg]*accg[0][reg] + accg[1][reg]*accg[1][reg]
                     + accg[2][reg]*accg[2][reg] + accg[3][reg]*accg[3][reg];
            #pragma unroll
            for (int m = 1; m <= 8; m <<= 1) {
                s1 += __shfl_xor(s1, m, 64);
                s2 += __shfl_xor(s2, m, 64);
            }
            const float mu  = s1 * (1.f/64.f);
            const float var = s2 * (1.f/64.f) - mu*mu;
            const float rs  = rsqrtf(var + 1e-5f);
            #pragma unroll
            for (int nt = 0; nt < 4; ++nt) {
                float h = (accg[nt][reg] - mu) * rs * gv[nt] + ev[nt];
                h = h > 0.f ? h : 0.01f*h;
                sH[(m0 + q*4 + reg) * SHS + nt*16 + n15] = f2b(h);
            }
        }
        // leaky on accf -> dF (in place)
        #pragma unroll
        for (int nt = 0; nt < 4; ++nt)
            #pragma unroll
            for (int reg = 0; reg < 4; ++reg) {
                const float v = accf[nt][reg];
                accf[nt][reg] = v > 0.f ? v : 0.01f*v;
            }
    }
    // no barrier: sH rows are wave-private

    // ---- stage B: h @ W2S -> leaky -> dM; select d; write d -> sH ----
    {
        f32x4 acch[4];
        #pragma unroll
        for (int nt = 0; nt < 4; ++nt) {
            const float b = b2s[nt*16 + n15];
            acch[nt] = (f32x4){b, b, b, b};
        }
        bf16x8 ah[2];
        #pragma unroll
        for (int kc = 0; kc < 2; ++kc)
            ah[kc] = *(const bf16x8*)&sH[(m0 + n15) * SHS + kc*32 + kq];
        #pragma unroll
        for (int kc = 0; kc < 2; ++kc) {
            bf16x8 bw[4];
            #pragma unroll
            for (int nt = 0; nt < 4; ++nt)
                bw[nt] = *(const bf16x8*)&wt[W2SF + ((nt*2 + kc)*64 + lane)*8];
            #pragma unroll
            for (int nt = 0; nt < 4; ++nt)
                acch[nt] = __builtin_amdgcn_mfma_f32_16x16x32_bf16(ah[kc], bw[nt], acch[nt], 0, 0, 0);
        }
        #pragma unroll
        for (int reg = 0; reg < 4; ++reg) {
            const int row = m0 + q*4 + reg;
            const bool masked = (sRank[row] < 0);
            #pragma unroll
            for (int nt = 0; nt < 4; ++nt) {
                float dm = acch[nt][reg];
                dm = dm > 0.f ? dm : 0.01f*dm;
                const float d = masked ? dm : accf[nt][reg];
                sH[row * SHS + nt*16 + n15] = f2b(d);
            }
        }
    }
    // no barrier: wave-private rows again

    // ---- stage C: d @ ssc_w -> sOut ----
    {
        f32x4 accs[2];
        #pragma unroll
        for (int nt = 0; nt < 2; ++nt) {
            const int col = nt*16 + n15;
            const float b = (col < NCLS) ? sscb[col] : 0.f;
            accs[nt] = (f32x4){b, b, b, b};
        }
        bf16x8 ad[2];
        #pragma unroll
        for (int kc = 0; kc < 2; ++kc)
            ad[kc] = *(const bf16x8*)&sH[(m0 + n15) * SHS + kc*32 + kq];
        #pragma unroll
        for (int kc = 0; kc < 2; ++kc) {
            bf16x8 bw[2];
            #pragma unroll
            for (int nt = 0; nt < 2; ++nt)
                bw[nt] = *(const bf16x8*)&wt[SSCF + ((nt*2 + kc)*64 + lane)*8];
            #pragma unroll
            for (int nt = 0; nt < 2; ++nt)
                accs[nt] = __builtin_amdgcn_mfma_f32_16x16x32_bf16(ad[kc], bw[nt], accs[nt], 0, 0, 0);
        }
        #pragma unroll
        for (int reg = 0; reg < 4; ++reg) {
            const int row = m0 + q*4 + reg;
            sOut[row*SOS + n15] = accs[0][reg];
            if (n15 < 4) sOut[row*SOS + 16 + n15] = accs[1][reg];
        }
    }
    __syncthreads();   // barrier 2: sOut complete (cross-wave readback)

    // ---- coalesced SSC store: out[ch][p0+vox] <- sOut[vox][ch] ----
    #pragma unroll
    for (int jj = 0; jj < 5; ++jj) {
        const int i = tid + jj*256;       // i = ch*64 + vox
        out[(size_t)(i >> 6) * NVOX + p0 + (i & 63)] = sOut[(i & 63) * SOS + (i >> 6)];
    }
}

extern "C" void kernel_launch(void* const* d_in, const int* in_sizes, int n_in,
                              void* d_out, int out_size, void* d_ws, size_t ws_size,
                              hipStream_t stream) {
    const float* x3d  = (const float*)d_in[0];
    const float* w1   = (const float*)d_in[1];
    const float* b1   = (const float*)d_in[2];
    const float* lng  = (const float*)d_in[3];
    const float* lnb  = (const float*)d_in[4];
    const float* w2   = (const float*)d_in[5];
    const float* bb2  = (const float*)d_in[6];
    const float* sdbw = (const float*)d_in[7];
    const float* sdbb = (const float*)d_in[8];
    const float* sscw = (const float*)d_in[9];
    const float* sscb = (const float*)d_in[10];
    const float* auxw = (const float*)d_in[11];
    const float* auxb = (const float*)d_in[12];
    const int*   uidx = (const int*)d_in[13];
    const int*   midx = (const int*)d_in[14];
    float* out = (float*)d_out;
    u16*   wt  = (u16*)d_ws;
    const float* b2s  = (const float*)((const char*)d_ws + B2S_BYTE);
    const int*   rank = (const int*)((const char*)d_ws + RANK_BYTE);

    hipLaunchKernelGGL(prep_weights, dim3(128), dim3(256), 0, stream,
                       w1, w2, bb2, sdbw, sdbb, sscw, auxw, uidx, midx, wt);
    hipLaunchKernelGGL(sgn_mfma, dim3(NBLK), dim3(256), 0, stream,
                       x3d, b1, lng, lnb, b2s, sdbb, sscb, auxb,
                       rank, wt, out);
}